// Round 5
// baseline (318.955 us; speedup 1.0000x reference)
//
#include <hip/hip_runtime.h>

#define N 4096            // row length
#define NEG_BIG -9999999.9f
#define CAP 256           // candidate buffer capacity per row

typedef float floatx4 __attribute__((ext_vector_type(4)));

// Four waves (256 threads) per row, one row per block; 16 elems/lane.
// The whole quarter-row (4 float4 of x + 4 of mask) is loaded into registers
// in ONE burst of 8 global_load_dwordx4 -> 8 KB in flight per wave (the
// round-4 structure only sustained ~2 loads in flight; MLP was the limiter).
// __launch_bounds__(256,8) pins the 64-VGPR/8-wave tier; true need ~55 so no
// spill (rounds 2-3 spilled because the cap was BELOW true need).
// tau via Newton on the tiny candidate set {z > rmax-1} (provably contains
// the sparsemax support); all lanes run it redundantly from LDS broadcasts.
__global__ __launch_bounds__(256, 8)
void sparsemax_kernel(const float* __restrict__ x,
                      const float* __restrict__ m,
                      float* __restrict__ out) {
    const int lane = threadIdx.x & 63;
    const int wave = threadIdx.x >> 6;           // 0..3
    const int row  = blockIdx.x;

    __shared__ float  smax[4];
    __shared__ float2 sparts[2][4];              // [parity][wave] fallback partials
    __shared__ float  cand[CAP];                 // w = z - rmax of candidates
    __shared__ int    cnt;
    if (threadIdx.x == 0) cnt = 0;

    // Each wave owns a quarter-row: 1024 elems = 256 float4, lane-strided.
    const size_t base = (size_t)row * (N / 4) + (size_t)wave * (N / 16);
    const float4* __restrict__ xr = (const float4*)x + base;
    const float4* __restrict__ mr = (const float4*)m + base;
    float4* __restrict__ outr     = (float4*)out + base;

    // One burst: all 8 loads issued before any consumption.
    float4 xv0 = xr[0 * 64 + lane];
    float4 xv1 = xr[1 * 64 + lane];
    float4 xv2 = xr[2 * 64 + lane];
    float4 xv3 = xr[3 * 64 + lane];
    float4 mv0 = mr[0 * 64 + lane];
    float4 mv1 = mr[1 * 64 + lane];
    float4 mv2 = mr[2 * 64 + lane];
    float4 mv3 = mr[3 * 64 + lane];

    // z = (mask ? x : NEG_BIG) * 2   (/(1-TEMP), TEMP=0.5)
    float z[16];
#define FOLD(k, xv, mv)                                        \
    z[4 * k + 0] = (mv.x != 0.0f ? xv.x : NEG_BIG) * 2.0f;     \
    z[4 * k + 1] = (mv.y != 0.0f ? xv.y : NEG_BIG) * 2.0f;     \
    z[4 * k + 2] = (mv.z != 0.0f ? xv.z : NEG_BIG) * 2.0f;     \
    z[4 * k + 3] = (mv.w != 0.0f ? xv.w : NEG_BIG) * 2.0f;
    FOLD(0, xv0, mv0)
    FOLD(1, xv1, mv1)
    FOLD(2, xv2, mv2)
    FOLD(3, xv3, mv3)
#undef FOLD

    float rmax = -3.0e38f;
#pragma unroll
    for (int i = 0; i < 16; ++i) rmax = fmaxf(rmax, z[i]);

    // Wave-wide max butterfly, then cross-wave combine via LDS.
#pragma unroll
    for (int k = 32; k >= 1; k >>= 1)
        rmax = fmaxf(rmax, __shfl_xor(rmax, k, 64));
    if (lane == 0) smax[wave] = rmax;
    __syncthreads();                              // smax + cnt=0 visible
    rmax = fmaxf(fmaxf(smax[0], smax[1]), fmaxf(smax[2], smax[3]));

    // Append candidates w = z - rmax with w > -1 (support must lie here,
    // since sum_support(z - tau) = 1 implies tau >= rmax - 1).
    const float thr0 = rmax - 1.0f;
#pragma unroll
    for (int i = 0; i < 16; ++i) {
        if (z[i] > thr0) {
            int idx = atomicAdd(&cnt, 1);
            if (idx < CAP) cand[idx] = z[i] - rmax;
        }
    }
    __syncthreads();                              // appends visible

    const int K = cnt;                            // block-uniform
    float u = -1.0f;                              // solve sum max(w-u,0)=1
    if (K <= CAP) {
        // Tiny-set Newton, identical on every lane (LDS broadcasts).
        for (int it = 0; it < 32; ++it) {
            float s = 0.0f, c = 0.0f;
            for (int j = 0; j < K; ++j) {
                float v = cand[j] - u;
                if (v > 0.0f) { s += v; c += 1.0f; }
            }
            float un = u + (s - 1.0f) / c;        // monotone non-decreasing
            if (!(un > u)) break;                 // exact fixed point
            u = un;
        }
    } else {
        // Fallback over the full row (e.g. all-masked: all w == 0).
        // K block-uniform -> all waves here; u sequence identical on every
        // wave -> the break is block-uniform. Double-buffered partials ->
        // one barrier per iteration.
        int parity = 0;
        for (int it = 0; it < 32; ++it) {
            float s = 0.0f, c = 0.0f;
#pragma unroll
            for (int i = 0; i < 16; ++i) {
                float v = (z[i] - rmax) - u;
                if (v > 0.0f) { s += v; c += 1.0f; }
            }
#pragma unroll
            for (int k = 32; k >= 1; k >>= 1) {
                s += __shfl_xor(s, k, 64);
                c += __shfl_xor(c, k, 64);
            }
            if (lane == 0) sparts[parity][wave] = make_float2(s, c);
            __syncthreads();
            float S = 0.0f, C = 0.0f;
#pragma unroll
            for (int w = 0; w < 4; ++w) {
                float2 p = sparts[parity][w];
                S += p.x; C += p.y;
            }
            float un = u + (S - 1.0f) / C;
            parity ^= 1;
            if (!(un > u)) break;
            u = un;
        }
    }

    // All-masked row: reference multiplies by mask -> exact zeros.
    const float live = (rmax == NEG_BIG * 2.0f) ? 0.0f : 1.0f;
    const float thr  = rmax + u;                  // = tau

    // Nontemporal stores: out is written once, never read -> don't evict
    // input lines from L2/L3.
#pragma unroll
    for (int j = 0; j < 4; ++j) {
        floatx4 o;
        o.x = fmaxf(z[4 * j + 0] - thr, 0.0f) * live;
        o.y = fmaxf(z[4 * j + 1] - thr, 0.0f) * live;
        o.z = fmaxf(z[4 * j + 2] - thr, 0.0f) * live;
        o.w = fmaxf(z[4 * j + 3] - thr, 0.0f) * live;
        __builtin_nontemporal_store(o, (floatx4*)&outr[j * 64 + lane]);
    }
}

extern "C" void kernel_launch(void* const* d_in, const int* in_sizes, int n_in,
                              void* d_out, int out_size, void* d_ws, size_t ws_size,
                              hipStream_t stream) {
    const float* x = (const float*)d_in[0];
    const float* m = (const float*)d_in[1];
    float* out = (float*)d_out;
    const int rows = in_sizes[0] / N;             // 8192
    sparsemax_kernel<<<rows, 256, 0, stream>>>(x, m, out);
}